// Round 5
// baseline (169.118 us; speedup 1.0000x reference)
//
#include <hip/hip_runtime.h>
#include <hip/hip_bf16.h>

// phi = exp(-d2/(2*ls^2)) = exp2(-S2*d2), S2 = 1/(2*0.3^2*ln2) = 8.014973
// Expanded: exp2(2*S2*(x.c) - S2*|x|^2 - S2*|c|^2)
// Center pack (64 B, all operands duplicated for VOP3P sgpr-pair broadcast):
//   [K2cx,K2cx, K2cy,K2cy, K2cz,K2cz, aw,aw, u,u, v,v, w,w, 0,0]
//   where aw = -S2*|c|^2.  Per-lane PX = -S2*|x|^2 (exponent <= 0 always).
#define S2 8.014973f
#define K2 16.029946f
#define NCHUNK 21
#define PER 162              // even; NCHUNK*PER = 3402 >= M = 3375
#define MPAD (NCHUNK * PER)  // dummy centers: zero coeffs -> contribute 0

typedef float f2 __attribute__((ext_vector_type(2)));
typedef float f16v __attribute__((ext_vector_type(16)));

// d += a * b_sgpr_pair  (VOP3P packed fp32: 2 lanes of fp32 per instruction,
// one SGPR-pair source allowed -> center operands never touch the VALU)
#define PKFMA_ACC(d, a, b) \
    asm("v_pk_fma_f32 %0, %1, %2, %0" : "+v"(d) : "v"(a), "s"(b))
#define PKADD(d, a, b) \
    asm("v_pk_add_f32 %0, %1, %2" : "=v"(d) : "v"(a), "s"(b))

__global__ void rbf_prep_kernel(const float* __restrict__ centers,
                                const float* __restrict__ cu,
                                const float* __restrict__ cv,
                                const float* __restrict__ cw,
                                float* __restrict__ cp16, int M) {
    int m = blockIdx.x * 256 + threadIdx.x;
    if (m < MPAD + 2) {  // +2: prefetch overshoot target, zeroed
        float ax = 0.f, ay = 0.f, az = 0.f, aw = 0.f, u = 0.f, v = 0.f,
              w = 0.f;
        if (m < M) {
            float cx = centers[3 * m + 0];
            float cy = centers[3 * m + 1];
            float cz = centers[3 * m + 2];
            ax = K2 * cx;
            ay = K2 * cy;
            az = K2 * cz;
            aw = -S2 * (cx * cx + cy * cy + cz * cz);
            u = cu[m];
            v = cv[m];
            w = cw[m];
        }
        float* o = cp16 + (size_t)m * 16;
        o[0] = ax;  o[1] = ax;
        o[2] = ay;  o[3] = ay;
        o[4] = az;  o[5] = az;
        o[6] = aw;  o[7] = aw;
        o[8] = u;   o[9] = u;
        o[10] = v;  o[11] = v;
        o[12] = w;  o[13] = w;
        o[14] = 0.f; o[15] = 0.f;
    }
}

// One full center evaluated against this wave's 256 points (4/lane in two
// f2 groups). 14 pk-fp32 + 4 exp per center-wave = ~60 issue cycles.
#define CENTER(C)                                                     \
    {                                                                 \
        f2 axd = __builtin_shufflevector(C, C, 0, 1);                 \
        f2 ayd = __builtin_shufflevector(C, C, 2, 3);                 \
        f2 azd = __builtin_shufflevector(C, C, 4, 5);                 \
        f2 awd = __builtin_shufflevector(C, C, 6, 7);                 \
        f2 ud = __builtin_shufflevector(C, C, 8, 9);                  \
        f2 vd = __builtin_shufflevector(C, C, 10, 11);                \
        f2 wd = __builtin_shufflevector(C, C, 12, 13);                \
        f2 t0, t1, ph0, ph1;                                          \
        PKADD(t0, PX0, awd);                                          \
        PKADD(t1, PX1, awd);                                          \
        PKFMA_ACC(t0, Z0, azd);                                       \
        PKFMA_ACC(t1, Z1, azd);                                       \
        PKFMA_ACC(t0, Y0, ayd);                                       \
        PKFMA_ACC(t1, Y1, ayd);                                       \
        PKFMA_ACC(t0, X0, axd);                                       \
        PKFMA_ACC(t1, X1, axd);                                       \
        ph0.x = __builtin_amdgcn_exp2f(t0.x);                         \
        ph0.y = __builtin_amdgcn_exp2f(t0.y);                         \
        ph1.x = __builtin_amdgcn_exp2f(t1.x);                         \
        ph1.y = __builtin_amdgcn_exp2f(t1.y);                         \
        PKFMA_ACC(AU0, ph0, ud);                                      \
        PKFMA_ACC(AU1, ph1, ud);                                      \
        PKFMA_ACC(AV0, ph0, vd);                                      \
        PKFMA_ACC(AV1, ph1, vd);                                      \
        PKFMA_ACC(AW0, ph0, wd);                                      \
        PKFMA_ACC(AW1, ph1, wd);                                      \
    }

// Wave-task pool: task = (256-point tile) x (162-center chunk); 391*21 = 8211
// tasks over 8192 waves (grid 2048x256) -> balanced, ~full occupancy.
// Centers via s_load_dwordx16 ping-pong (no register copies, 1 outstanding
// SMEM op at each wait). Partial sums -> fp32 global atomics.
__global__ __launch_bounds__(256) void rbf_main_kernel(
    const float* __restrict__ x, const float* __restrict__ cp16,
    float* __restrict__ out, int N, int NT, int ntask) {
    const int lane = threadIdx.x & 63;
    const int wid =
        __builtin_amdgcn_readfirstlane(blockIdx.x * 4 + (threadIdx.x >> 6));
    const int nwaves = gridDim.x * 4;

    for (int task = wid; task < ntask; task += nwaves) {
        const int tile = task % NT;   // uniform
        const int chunk = task / NT;  // uniform

        float xs[4], ys[4], zs[4];
        int p[4];
#pragma unroll
        for (int q = 0; q < 4; ++q) {
            int pp = tile * 256 + q * 64 + lane;
            p[q] = pp;
            float a = 0.f, b = 0.f, c = 0.f;
            if (pp < N) {
                a = x[3 * pp + 0];
                b = x[3 * pp + 1];
                c = x[3 * pp + 2];
            }
            xs[q] = a;
            ys[q] = b;
            zs[q] = c;
        }
        const f2 X0 = {xs[0], xs[1]}, X1 = {xs[2], xs[3]};
        const f2 Y0 = {ys[0], ys[1]}, Y1 = {ys[2], ys[3]};
        const f2 Z0 = {zs[0], zs[1]}, Z1 = {zs[2], zs[3]};
        const f2 PX0 = {-S2 * (xs[0] * xs[0] + ys[0] * ys[0] + zs[0] * zs[0]),
                        -S2 * (xs[1] * xs[1] + ys[1] * ys[1] + zs[1] * zs[1])};
        const f2 PX1 = {-S2 * (xs[2] * xs[2] + ys[2] * ys[2] + zs[2] * zs[2]),
                        -S2 * (xs[3] * xs[3] + ys[3] * ys[3] + zs[3] * zs[3])};

        f2 AU0 = {0.f, 0.f}, AU1 = {0.f, 0.f};
        f2 AV0 = {0.f, 0.f}, AV1 = {0.f, 0.f};
        f2 AW0 = {0.f, 0.f}, AW1 = {0.f, 0.f};

        uint64_t ap = (uint64_t)(const void*)(cp16 + (size_t)chunk * PER * 16);
        f16v c0, c1;
        asm volatile("s_load_dwordx16 %0, %1, 0x0" : "=s"(c0) : "s"(ap));
        asm volatile("s_waitcnt lgkmcnt(0)" : "+s"(c0));
#pragma unroll 1
        for (int it = 0; it < PER / 2; ++it) {
            asm volatile("s_load_dwordx16 %0, %1, 0x40" : "=s"(c1) : "s"(ap));
            CENTER(c0);  // ~60 cyc covers the c1 SMEM latency
            asm volatile("s_waitcnt lgkmcnt(0)" : "+s"(c1));
            asm volatile("s_load_dwordx16 %0, %1, 0x80" : "=s"(c0) : "s"(ap));
            CENTER(c1);
            asm volatile("s_waitcnt lgkmcnt(0)" : "+s"(c0));
            ap += 128;
        }

        float au[4] = {AU0.x, AU0.y, AU1.x, AU1.y};
        float av[4] = {AV0.x, AV0.y, AV1.x, AV1.y};
        float aw[4] = {AW0.x, AW0.y, AW1.x, AW1.y};

        if (chunk == 0) {  // fold base field x*(1-||x||) once per point
#pragma unroll
            for (int q = 0; q < 4; ++q) {
                float g = 1.f - sqrtf(xs[q] * xs[q] + ys[q] * ys[q] +
                                      zs[q] * zs[q]);
                au[q] += xs[q] * g;
                av[q] += ys[q] * g;
                aw[q] += zs[q] * g;
            }
        }
#pragma unroll
        for (int q = 0; q < 4; ++q) {
            if (p[q] < N) {
                atomicAdd(&out[3 * p[q] + 0], au[q]);
                atomicAdd(&out[3 * p[q] + 1], av[q]);
                atomicAdd(&out[3 * p[q] + 2], aw[q]);
            }
        }
    }
}

extern "C" void kernel_launch(void* const* d_in, const int* in_sizes, int n_in,
                              void* d_out, int out_size, void* d_ws,
                              size_t ws_size, hipStream_t stream) {
    const float* x = (const float*)d_in[0];
    const float* centers = (const float*)d_in[1];
    const float* cu = (const float*)d_in[2];
    const float* cv = (const float*)d_in[3];
    const float* cw = (const float*)d_in[4];
    const int N = in_sizes[0] / 3;
    const int M = in_sizes[1] / 3;
    float* cp16 = (float*)d_ws;
    float* out = (float*)d_out;

    const int NT = (N + 255) / 256;  // 391
    const int ntask = NT * NCHUNK;   // 8211

    hipLaunchKernelGGL(rbf_prep_kernel, dim3((MPAD + 2 + 255) / 256), dim3(256),
                       0, stream, centers, cu, cv, cw, cp16, M);
    hipMemsetAsync(d_out, 0, (size_t)out_size * sizeof(float), stream);
    hipLaunchKernelGGL(rbf_main_kernel, dim3(2048), dim3(256), 0, stream, x,
                       cp16, out, N, NT, ntask);
}